// Round 5
// baseline (285.622 us; speedup 1.0000x reference)
//
#include <hip/hip_runtime.h>
#include <hip/hip_bf16.h>

// MHA block: B=2, S=2048, D=1024, H=16, DK=64, causal. fp32 in/out.
// ROUND 14: round-13 pipelined attention, restructured without lambdas
// (macro bodies on named locals; explicit parity-unrolled loop) after two
// container failures on the lambda version. Algorithm identical:
// step u = QK[u] | issue K[u+4],V[u] | exp | PV[u-4] | store P[u].
// P LDS double-buffer unioned with combine buffer; shift-free split-K
// combine; paired qtiles; XCD-resident bh mapping. GEMMs unchanged.

typedef __bf16 bf16_t;
typedef __bf16 bf16x4 __attribute__((ext_vector_type(4)));
typedef __bf16 bf16x8 __attribute__((ext_vector_type(8)));
typedef float f32x4 __attribute__((ext_vector_type(4)));

#define BB 2
#define SS 2048
#define DD 1024
#define HH 16
#define DKK 64
#define MM 4096            // tokens = B*S

#define NELT ((size_t)BB * SS * DD)     // 4,194,304
#define WELT ((size_t)DD * DD)          // 1,048,576

// layout: Qp | Kp | Vt | Xa | qb | kb | vb | Wqb | Wkb | Wvb | Wob
__device__ __align__(16) bf16_t g_ws[7 * NELT + 4 * WELT];

// async global->LDS, 16 B/lane; LDS dest = wave-uniform base + lane*16
__device__ __forceinline__ void gld16(const bf16_t* g, bf16_t* l) {
    __builtin_amdgcn_global_load_lds(
        (const __attribute__((address_space(1))) void*)g,
        (__attribute__((address_space(3))) void*)l, 16, 0, 0);
}

// ---------------------------------------------------------------------------
// fp32 -> bf16 pre-convert
// ---------------------------------------------------------------------------
__global__ __launch_bounds__(256) void cvt7(
    const float* __restrict__ q,  const float* __restrict__ k,  const float* __restrict__ v,
    const float* __restrict__ Wq, const float* __restrict__ Wk, const float* __restrict__ Wv,
    const float* __restrict__ Wo,
    bf16_t* __restrict__ qb, bf16_t* __restrict__ kb, bf16_t* __restrict__ vb,
    bf16_t* __restrict__ Wqb, bf16_t* __restrict__ Wkb, bf16_t* __restrict__ Wvb,
    bf16_t* __restrict__ Wob)
{
    const float* s; bf16_t* d; size_t n;
    switch (blockIdx.y) {
        case 0: s = q;  d = qb;  n = NELT; break;
        case 1: s = k;  d = kb;  n = NELT; break;
        case 2: s = v;  d = vb;  n = NELT; break;
        case 3: s = Wq; d = Wqb; n = WELT; break;
        case 4: s = Wk; d = Wkb; n = WELT; break;
        case 5: s = Wv; d = Wvb; n = WELT; break;
        default: s = Wo; d = Wob; n = WELT; break;
    }
    size_t e = ((size_t)blockIdx.x * 256 + threadIdx.x) * 8;
    if (e >= n) return;
    f32x4 a = *(const f32x4*)(s + e);
    f32x4 b = *(const f32x4*)(s + e + 4);
    bf16x8 o;
    #pragma unroll
    for (int i = 0; i < 4; ++i) { o[i] = (bf16_t)a[i]; o[4 + i] = (bf16_t)b[i]; }
    *(bf16x8*)(d + e) = o;
}

// ---------------------------------------------------------------------------
// Fused QKV projection: BM=BN=128, BK=64, 4 waves x (4x4 MFMA x 2 k-steps).
// z=0: Qp=(q@Wq^T+bq)*0.125 ; z=1: Kp ; z=2: Vt (transposed store)
// ---------------------------------------------------------------------------
#define BM 128
#define BN 128
#define BKG 64
#define LDC 136

__global__ __launch_bounds__(256) void gemm_qkv3(
    const bf16_t* __restrict__ qb, const bf16_t* __restrict__ kb, const bf16_t* __restrict__ vb,
    const bf16_t* __restrict__ Wqb, const bf16_t* __restrict__ Wkb, const bf16_t* __restrict__ Wvb,
    const float* __restrict__ bq, const float* __restrict__ bk, const float* __restrict__ bv,
    bf16_t* __restrict__ Qp, bf16_t* __restrict__ Kp, bf16_t* __restrict__ Vt)
{
    const int z = blockIdx.z;
    const bf16_t* A    = (z == 0) ? qb  : (z == 1) ? kb  : vb;
    const bf16_t* W    = (z == 0) ? Wqb : (z == 1) ? Wkb : Wvb;
    const float*  bias = (z == 0) ? bq  : (z == 1) ? bk  : bv;

    // union: As[128][64] + Bs[128][64] (32 KB) vs Ct[128][LDC] (34.8 KB)
    __shared__ __align__(16) bf16_t smem[128 * LDC];
    bf16_t (*As)[BKG] = (bf16_t(*)[BKG])smem;
    bf16_t (*Bs)[BKG] = (bf16_t(*)[BKG])(smem + 128 * BKG);
    bf16_t (*Ct)[LDC] = (bf16_t(*)[LDC])smem;

    const int tid  = threadIdx.x;
    const int wave = tid >> 6;
    const int lane = tid & 63;
    const int quad = lane >> 4;
    const int c16  = lane & 15;
    const int bm = blockIdx.x * BM;
    const int bn = blockIdx.y * BN;
    const int wm = (wave >> 1) * 64;
    const int wn = (wave & 1) * 64;

    const int srow = lane >> 3;        // 0..7 within an 8-row chunk
    const int scol = (lane & 7) * 8;   // 0..56

    f32x4 acc[4][4] = {};

    for (int k0 = 0; k0 < DD; k0 += BKG) {
        __syncthreads();
        #pragma unroll
        for (int j = 0; j < 4; ++j) {
            int r0 = wave * 32 + j * 8;
            gld16(A + (size_t)(bm + r0 + srow) * DD + k0 + scol, &As[r0][0]);
            gld16(W + (size_t)(bn + r0 + srow) * DD + k0 + scol, &Bs[r0][0]);
        }
        __syncthreads();   // drains vmcnt -> async LDS writes complete

        #pragma unroll
        for (int ks = 0; ks < 2; ++ks) {
            bf16x8 af[4], bfr[4];
            #pragma unroll
            for (int tm = 0; tm < 4; ++tm)
                af[tm] = *(const bf16x8*)(&As[wm + tm * 16 + c16][ks * 32 + quad * 8]);
            #pragma unroll
            for (int tn = 0; tn < 4; ++tn)
                bfr[tn] = *(const bf16x8*)(&Bs[wn + tn * 16 + c16][ks * 32 + quad * 8]);
            #pragma unroll
            for (int tm = 0; tm < 4; ++tm)
                #pragma unroll
                for (int tn = 0; tn < 4; ++tn)
                    acc[tm][tn] = __builtin_amdgcn_mfma_f32_16x16x32_bf16(
                        af[tm], bfr[tn], acc[tm][tn], 0, 0, 0);
        }
    }

    float bia[4];
    #pragma unroll
    for (int tn = 0; tn < 4; ++tn)
        bia[tn] = bias[bn + wn + tn * 16 + c16];

    if (z < 2) {
        const float osc = (z == 0) ? 0.125f : 1.0f;
        bf16_t* C = (z == 0) ? Qp : Kp;
        #pragma unroll
        for (int tm = 0; tm < 4; ++tm)
            #pragma unroll
            for (int r = 0; r < 4; ++r) {
                size_t base = (size_t)(bm + wm + tm * 16 + quad * 4 + r) * DD;
                #pragma unroll
                for (int tn = 0; tn < 4; ++tn)
                    C[base + bn + wn + tn * 16 + c16] =
                        (bf16_t)((acc[tm][tn][r] + bia[tn]) * osc);
            }
    } else {
        __syncthreads();
        #pragma unroll
        for (int tm = 0; tm < 4; ++tm)
            #pragma unroll
            for (int tn = 0; tn < 4; ++tn) {
                bf16x4 pk;
                #pragma unroll
                for (int r = 0; r < 4; ++r)
                    pk[r] = (bf16_t)(acc[tm][tn][r] + bia[tn]);
                *(bf16x4*)(&Ct[wn + tn * 16 + c16][wm + tm * 16 + quad * 4]) = pk;
            }
        __syncthreads();
        const int b_    = bm >> 11;
        const int sbase = bm & (SS - 1);
        #pragma unroll
        for (int p = 0; p < 4; ++p) {
            int col = p * 32 + (tid >> 3);
            int si  = (tid & 7) * 8;
            size_t rowoff = (size_t)(b_ * 1024 + bn + col) * SS + sbase;
            #pragma unroll
            for (int half = 0; half < 2; ++half) {
                int s = si + half * 64;
                *(bf16x8*)(&Vt[rowoff + s]) = *(const bf16x8*)(&Ct[col][s]);
            }
        }
    }
}

// ---------------------------------------------------------------------------
// Output projection: BM=128, BN=64, BK=64 -> grid (32,16)=512 blocks.
// Wave tile 64x32 (4 tm x 2 tn).
// ---------------------------------------------------------------------------
__global__ __launch_bounds__(256) void gemm_out(
    const bf16_t* __restrict__ A,    // Xa [M,K]
    const bf16_t* __restrict__ W,    // Wob [N,K]
    const float* __restrict__ bias,
    float* __restrict__ C)
{
    __shared__ __align__(16) bf16_t As[128][BKG];
    __shared__ __align__(16) bf16_t Bs[64][BKG];

    const int tid  = threadIdx.x;
    const int wave = tid >> 6;
    const int lane = tid & 63;
    const int quad = lane >> 4;
    const int c16  = lane & 15;
    const int bm = blockIdx.x * 128;
    const int bn = blockIdx.y * 64;
    const int wm = (wave >> 1) * 64;
    const int wn = (wave & 1) * 32;

    const int srow = lane >> 3;
    const int scol = (lane & 7) * 8;

    f32x4 acc[4][2] = {};

    for (int k0 = 0; k0 < DD; k0 += BKG) {
        __syncthreads();
        #pragma unroll
        for (int j = 0; j < 4; ++j) {
            int r0 = wave * 32 + j * 8;
            gld16(A + (size_t)(bm + r0 + srow) * DD + k0 + scol, &As[r0][0]);
        }
        #pragma unroll
        for (int j = 0; j < 2; ++j) {
            int r0 = wave * 16 + j * 8;
            gld16(W + (size_t)(bn + r0 + srow) * DD + k0 + scol, &Bs[r0][0]);
        }
        __syncthreads();

        #pragma unroll
        for (int ks = 0; ks < 2; ++ks) {
            bf16x8 af[4], bfr[2];
            #pragma unroll
            for (int tm = 0; tm < 4; ++tm)
                af[tm] = *(const bf16x8*)(&As[wm + tm * 16 + c16][ks * 32 + quad * 8]);
            #pragma unroll
            for (int tn = 0; tn < 2; ++tn)
                bfr[tn] = *(const bf16x8*)(&Bs[wn + tn * 16 + c16][ks * 32 + quad * 8]);
            #pragma unroll
            for (int tm = 0; tm < 4; ++tm)
                #pragma unroll
                for (int tn = 0; tn < 2; ++tn)
                    acc[tm][tn] = __builtin_amdgcn_mfma_f32_16x16x32_bf16(
                        af[tm], bfr[tn], acc[tm][tn], 0, 0, 0);
        }
    }

    float bia[2];
    #pragma unroll
    for (int tn = 0; tn < 2; ++tn)
        bia[tn] = bias[bn + wn + tn * 16 + c16];

    #pragma unroll
    for (int tm = 0; tm < 4; ++tm)
        #pragma unroll
        for (int r = 0; r < 4; ++r) {
            size_t base = (size_t)(bm + wm + tm * 16 + quad * 4 + r) * DD;
            #pragma unroll
            for (int tn = 0; tn < 2; ++tn)
                C[base + bn + wn + tn * 16 + c16] = acc[tm][tn][r] + bia[tn];
        }
}

// ---------------------------------------------------------------------------
// Split-K flash attention, paired qtiles, software-pipelined step.
// Grid = dim3(1024): bh = (id%8)*4 + id/256 (XCD-resident), pair = (id>>3)&31.
// Macro-structured pipeline (no lambdas). Per wave, units u=wave,wave+4,...
// ---------------------------------------------------------------------------
#define LDPS 40   // P row stride (bf16): rows=q(32), cols=key(32)
#define LDCF 68   // combine row stride (fp32)
#define PSLOT (4 * 32 * LDPS)   // bf16 elements per P slot

#define LOADK(KF, UU)                                                          \
do {                                                                           \
    const int kb_ = (UU) * 32;                                                 \
    const bf16_t* kp0 = Kb + (size_t)(kb_ + c16) * DD;                         \
    const bf16_t* kp1 = Kb + (size_t)(kb_ + 16 + c16) * DD;                    \
    KF[0][0] = *(const bf16x8*)(kp0 + quad * 8);                               \
    KF[0][1] = *(const bf16x8*)(kp0 + 32 + quad * 8);                          \
    KF[1][0] = *(const bf16x8*)(kp1 + quad * 8);                               \
    KF[1][1] = *(const bf16x8*)(kp1 + 32 + quad * 8);                          \
} while (0)

#define ATTN_STEP(UU, KFC, KFN, VFC, VFP, PW, PR, DOPV)                        \
do {                                                                           \
    const int kb_ = (UU) * 32;                                                 \
    f32x4 sc_[2][2];                                                           \
    _Pragma("unroll")                                                          \
    for (int tm = 0; tm < 2; ++tm)                                             \
        _Pragma("unroll")                                                      \
        for (int ct = 0; ct < 2; ++ct) {                                       \
            f32x4 s_ = {};                                                     \
            s_ = __builtin_amdgcn_mfma_f32_16x16x32_bf16(                      \
                     KFC[ct][0], qf[tm][0], s_, 0, 0, 0);                      \
            s_ = __builtin_amdgcn_mfma_f32_16x16x32_bf16(                      \
                     KFC[ct][1], qf[tm][1], s_, 0, 0, 0);                      \
            sc_[tm][ct] = s_;                                                  \
        }                                                                      \
    if ((UU) + 4 < U) LOADK(KFN, (UU) + 4);                                    \
    _Pragma("unroll")                                                          \
    for (int tn = 0; tn < 4; ++tn)                                             \
        VFC[tn] = *(const bf16x8*)(Vb + (size_t)(tn * 16 + c16) * SS           \
                                   + kb_ + quad * 8);                          \
    const bool needmask_ = (kb_ == qbase);                                     \
    bf16x4 w_[2][2];                                                           \
    _Pragma("unroll")                                                          \
    for (int tm = 0; tm < 2; ++tm) {                                           \
        const int qrow_ = qbase + tm * 16 + c16;                               \
        _Pragma("unroll")                                                      \
        for (int ct = 0; ct < 2; ++ct)                                         \
            _Pragma("unroll")                                                  \
            for (int r = 0; r < 4; ++r) {                                      \
                float s_ = sc_[tm][ct][r];                                     \
                if (needmask_ && (kb_ + ct * 16 + quad * 4 + r > qrow_))       \
                    s_ = -1e9f;                                                \
                float p_ = __expf(s_);                                         \
                lsum2[tm] += p_;                                               \
                w_[tm][ct][r] = (bf16_t)p_;                                    \
            }                                                                  \
    }                                                                          \
    if (DOPV) {                                                                \
        _Pragma("unroll")                                                      \
        for (int tm = 0; tm < 2; ++tm) {                                       \
            bf16x8 pa_ = *(const bf16x8*)((PR) + tm * 16 * LDPS);              \
            _Pragma("unroll")                                                  \
            for (int tn = 0; tn < 4; ++tn)                                     \
                oacc[tm][tn] = __builtin_amdgcn_mfma_f32_16x16x32_bf16(        \
                    pa_, VFP[tn], oacc[tm][tn], 0, 0, 0);                      \
        }                                                                      \
    }                                                                          \
    _Pragma("unroll")                                                          \
    for (int tm = 0; tm < 2; ++tm)                                             \
        _Pragma("unroll")                                                      \
        for (int ct = 0; ct < 2; ++ct)                                         \
            *(bf16x4*)((PW) + tm * 16 * LDPS + ct * 16) = w_[tm][ct];          \
} while (0)

#define PVFIN(PR, VFP)                                                         \
do {                                                                           \
    _Pragma("unroll")                                                          \
    for (int tm = 0; tm < 2; ++tm) {                                           \
        bf16x8 pa_ = *(const bf16x8*)((PR) + tm * 16 * LDPS);                  \
        _Pragma("unroll")                                                      \
        for (int tn = 0; tn < 4; ++tn)                                         \
            oacc[tm][tn] = __builtin_amdgcn_mfma_f32_16x16x32_bf16(            \
                pa_, VFP[tn], oacc[tm][tn], 0, 0, 0);                          \
    }                                                                          \
} while (0)

__global__ __launch_bounds__(256) void attn_fwd9(
    const bf16_t* __restrict__ Q,   // [B,S,D] (pre-scaled by 1/8)
    const bf16_t* __restrict__ K,   // [B,S,D]
    const bf16_t* __restrict__ Vt,  // [(b*1024 + h*64 + dk)][s]
    bf16_t* __restrict__ O)         // [B,S,D]
{
    const int flat = blockIdx.x;
    const int bh   = (flat & 7) * 4 + (flat >> 8);   // XCD-resident heads
    const int pair = (flat >> 3) & 31;
    const int b = bh >> 4;
    const int h = bh & 15;

    const int wave = threadIdx.x >> 6;
    const int lane = threadIdx.x & 63;
    const int quad = lane >> 4;
    const int c16  = lane & 15;

    // union: Ps[2][4][32][LDPS] bf16 (20.5 KB) / Cf[4][16][LDCF] fp32 (17.4 KB)
    __shared__ __align__(16) unsigned char smraw[2 * PSLOT * 2];
    bf16_t (*Ps)[4][32][LDPS] = (bf16_t(*)[4][32][LDPS])smraw;
    float  (*Cf)[16][LDCF]    = (float(*)[16][LDCF])smraw;
    __shared__ float Ls[4][32];

    const bf16_t* Kb = K  + (size_t)b * SS * DD + h * DKK;
    const bf16_t* Vb = Vt + (size_t)(b * 1024 + h * DKK) * SS;

    // per-lane LDS addresses for the two P slots
    bf16_t*       pw0 = &Ps[0][wave][c16][quad * 4];   // + tm*16*LDPS + ct*16
    const bf16_t* pr0 = &Ps[0][wave][c16][quad * 8];   // + tm*16*LDPS
    bf16_t*       pw1 = pw0 + PSLOT;
    const bf16_t* pr1 = pr0 + PSLOT;

    for (int t = 0; t < 2; ++t) {
        const int qt    = (t == 0) ? (63 - pair) : pair;   // heavy tile first
        const int qbase = qt * 32;
        const int U     = qt + 1;          // 32-key units

        // Q fragments (B operand of swapped MFMA): rows qbase..qbase+31
        bf16x8 qf[2][2];
        #pragma unroll
        for (int tm = 0; tm < 2; ++tm) {
            const bf16_t* qp = Q + ((size_t)b * SS + qbase + tm * 16 + c16) * DD + h * DKK;
            qf[tm][0] = *(const bf16x8*)(qp + quad * 8);
            qf[tm][1] = *(const bf16x8*)(qp + 32 + quad * 8);
        }

        f32x4 oacc[2][4] = {};
        float lsum2[2] = {0.f, 0.f};

        bf16x8 kfA[2][2], kfB[2][2];   // K fragment double buffer [ct][kstep]
        bf16x8 vfA[4], vfB[4];         // V fragment double buffer [tn]

        {
            int u = wave;
            if (u < U) {
                LOADK(kfA, u);
                // peeled first step: consume kfA, load vfA, write slot0, no PV
                ATTN_STEP(u, kfA, kfB, vfA, vfB, pw0, pr1, 0);
                u += 4;
                for (;;) {
                    if (u >= U) { PVFIN(pr0, vfA); break; }
                    ATTN_STEP(u, kfB, kfA, vfB, vfA, pw1, pr0, 1);
                    u += 4;
                    if (u >= U) { PVFIN(pr1, vfB); break; }
                    ATTN_STEP(u, kfA, kfB, vfA, vfB, pw0, pr1, 1);
                    u += 4;
                }
            }
        }

        // ---- per-wave row sums (reduce over quads) -> Ls ----
        #pragma unroll
        for (int tm = 0; tm < 2; ++tm) {
            float l = lsum2[tm];
            l += __shfl_xor(l, 16, 64);
            l += __shfl_xor(l, 32, 64);
            if (lane < 16) Ls[wave][tm * 16 + lane] = l;
        }

        // ---- combine partials: two tm-passes through Cf (aliases Ps) ----
        const int row = threadIdx.x >> 4;        // 0..15
        const int col = (threadIdx.x & 15) * 4;  // 0..60
        #pragma unroll
        for (int tm = 0; tm < 2; ++tm) {
            __syncthreads();   // tm=0: unit loops done (Ps free); tm=1: pass-0 reads done
            #pragma unroll
            for (int tn = 0; tn < 4; ++tn)
                #pragma unroll
                for (int r = 0; r < 4; ++r)
                    Cf[wave][quad * 4 + r][tn * 16 + c16] = oacc[tm][tn][r];
            __syncthreads();
            f32x4 ssum = {};
            #pragma unroll
            for (int p = 0; p < 4; ++p)
                ssum += *(const f32x4*)(&Cf[p][row][col]);
            float l = Ls[0][tm * 16 + row] + Ls[1][tm * 16 + row]
                    + Ls[2][tm * 16 + row] + Ls[3][tm * 16 + row];
            float inv = 1.0f / l;
            bf16x4 o;
            #pragma unroll
            for (int i = 0; i < 4; ++i) o[i] = (bf16_t)(ssum[i] * inv);
            *(bf16x4*)(&O[((size_t)b * SS + qbase + tm * 16 + row) * DD + h * DKK + col]) = o;
        }
        __syncthreads();   // tile end: Ps/Cf/Ls reusable by next tile
    }
}

// ---------------------------------------------------------------------------
extern "C" void kernel_launch(void* const* d_in, const int* in_sizes, int n_in,
                              void* d_out, int out_size, void* d_ws, size_t ws_size,
                              hipStream_t stream) {
    (void)in_sizes; (void)n_in; (void)out_size; (void)d_ws; (void)ws_size;
    const float* q  = (const float*)d_in[0];
    const float* k  = (const float*)d_in[1];
    const float* v  = (const float*)d_in[2];
    const float* Wq = (const float*)d_in[4];
    const float* bq = (const float*)d_in[5];
    const float* Wk = (const float*)d_in[6];
    const float* bk = (const float*)d_in[7];
    const float* Wv = (const float*)d_in[8];
    const float* bv = (const float*)d_in[9];
    const float* Wo = (const float*)d_in[10];
    const float* bo = (const float*)d_in[11];

    bf16_t* ws;
    hipGetSymbolAddress((void**)&ws, HIP_SYMBOL(g_ws));
    bf16_t* Qp  = ws;
    bf16_t* Kp  = Qp + NELT;
    bf16_t* Vt  = Kp + NELT;
    bf16_t* Xa  = Vt + NELT;
    bf16_t* qb  = Xa + NELT;
    bf16_t* kb  = qb + NELT;
    bf16_t* vb  = kb + NELT;
    bf16_t* Wqb = vb + NELT;
    bf16_t* Wkb = Wqb + WELT;
    bf16_t* Wvb = Wkb + WELT;
    bf16_t* Wob = Wvb + WELT;

    cvt7<<<dim3(2048, 7), 256, 0, stream>>>(q, k, v, Wq, Wk, Wv, Wo,
                                            qb, kb, vb, Wqb, Wkb, Wvb, Wob);

    gemm_qkv3<<<dim3(MM / BM, DD / BN, 3), 256, 0, stream>>>(
        qb, kb, vb, Wqb, Wkb, Wvb, bq, bk, bv, Qp, Kp, Vt);

    attn_fwd9<<<dim3(1024), 256, 0, stream>>>(Qp, Kp, Vt, Xa);

    gemm_out<<<dim3(MM / 128, DD / 64), 256, 0, stream>>>(Xa, Wob, bo, (float*)d_out);
}

// Round 7
// 285.302 us; speedup vs baseline: 1.0011x; 1.0011x over previous
//
#include <hip/hip_runtime.h>
#include <hip/hip_bf16.h>

// MHA block: B=2, S=2048, D=1024, H=16, DK=64, causal. fp32 in/out.
// ROUND 16: r15 with the compile fix (__exp2f -> __builtin_amdgcn_exp2f,
// the direct v_exp_f32 builtin; log2e is pre-folded into Q by gemm_qkv3).
// r15 design: single-buffered K/V register tiles (WAR via in-order issue;
// load-use distance one full step), immediate P stores, target <=128 VGPR
// so the uniform 4-blocks/CU grid is fully resident.
// Step u: QK[u] | pa<-PR | issue K[u+4] | exp2+P-store | PV[u-4] | issue V[u].
// P LDS double-buffer unioned with fp32 combine buffer; shift-free split-K
// combine; paired qtiles; XCD bh mapping. GEMMs unchanged.

typedef __bf16 bf16_t;
typedef __bf16 bf16x4 __attribute__((ext_vector_type(4)));
typedef __bf16 bf16x8 __attribute__((ext_vector_type(8)));
typedef float f32x4 __attribute__((ext_vector_type(4)));

#define BB 2
#define SS 2048
#define DD 1024
#define HH 16
#define DKK 64
#define MM 4096            // tokens = B*S

#define NELT ((size_t)BB * SS * DD)     // 4,194,304
#define WELT ((size_t)DD * DD)          // 1,048,576

// layout: Qp | Kp | Vt | Xa | qb | kb | vb | Wqb | Wkb | Wvb | Wob
__device__ __align__(16) bf16_t g_ws[7 * NELT + 4 * WELT];

// async global->LDS, 16 B/lane; LDS dest = wave-uniform base + lane*16
__device__ __forceinline__ void gld16(const bf16_t* g, bf16_t* l) {
    __builtin_amdgcn_global_load_lds(
        (const __attribute__((address_space(1))) void*)g,
        (__attribute__((address_space(3))) void*)l, 16, 0, 0);
}

// ---------------------------------------------------------------------------
// fp32 -> bf16 pre-convert
// ---------------------------------------------------------------------------
__global__ __launch_bounds__(256) void cvt7(
    const float* __restrict__ q,  const float* __restrict__ k,  const float* __restrict__ v,
    const float* __restrict__ Wq, const float* __restrict__ Wk, const float* __restrict__ Wv,
    const float* __restrict__ Wo,
    bf16_t* __restrict__ qb, bf16_t* __restrict__ kb, bf16_t* __restrict__ vb,
    bf16_t* __restrict__ Wqb, bf16_t* __restrict__ Wkb, bf16_t* __restrict__ Wvb,
    bf16_t* __restrict__ Wob)
{
    const float* s; bf16_t* d; size_t n;
    switch (blockIdx.y) {
        case 0: s = q;  d = qb;  n = NELT; break;
        case 1: s = k;  d = kb;  n = NELT; break;
        case 2: s = v;  d = vb;  n = NELT; break;
        case 3: s = Wq; d = Wqb; n = WELT; break;
        case 4: s = Wk; d = Wkb; n = WELT; break;
        case 5: s = Wv; d = Wvb; n = WELT; break;
        default: s = Wo; d = Wob; n = WELT; break;
    }
    size_t e = ((size_t)blockIdx.x * 256 + threadIdx.x) * 8;
    if (e >= n) return;
    f32x4 a = *(const f32x4*)(s + e);
    f32x4 b = *(const f32x4*)(s + e + 4);
    bf16x8 o;
    #pragma unroll
    for (int i = 0; i < 4; ++i) { o[i] = (bf16_t)a[i]; o[4 + i] = (bf16_t)b[i]; }
    *(bf16x8*)(d + e) = o;
}

// ---------------------------------------------------------------------------
// Fused QKV projection: BM=BN=128, BK=64, 4 waves x (4x4 MFMA x 2 k-steps).
// z=0: Qp=(q@Wq^T+bq)*(0.125*log2e) ; z=1: Kp ; z=2: Vt (transposed store)
// ---------------------------------------------------------------------------
#define BM 128
#define BN 128
#define BKG 64
#define LDC 136

__global__ __launch_bounds__(256) void gemm_qkv3(
    const bf16_t* __restrict__ qb, const bf16_t* __restrict__ kb, const bf16_t* __restrict__ vb,
    const bf16_t* __restrict__ Wqb, const bf16_t* __restrict__ Wkb, const bf16_t* __restrict__ Wvb,
    const float* __restrict__ bq, const float* __restrict__ bk, const float* __restrict__ bv,
    bf16_t* __restrict__ Qp, bf16_t* __restrict__ Kp, bf16_t* __restrict__ Vt)
{
    const int z = blockIdx.z;
    const bf16_t* A    = (z == 0) ? qb  : (z == 1) ? kb  : vb;
    const bf16_t* W    = (z == 0) ? Wqb : (z == 1) ? Wkb : Wvb;
    const float*  bias = (z == 0) ? bq  : (z == 1) ? bk  : bv;

    // union: As[128][64] + Bs[128][64] (32 KB) vs Ct[128][LDC] (34.8 KB)
    __shared__ __align__(16) bf16_t smem[128 * LDC];
    bf16_t (*As)[BKG] = (bf16_t(*)[BKG])smem;
    bf16_t (*Bs)[BKG] = (bf16_t(*)[BKG])(smem + 128 * BKG);
    bf16_t (*Ct)[LDC] = (bf16_t(*)[LDC])smem;

    const int tid  = threadIdx.x;
    const int wave = tid >> 6;
    const int lane = tid & 63;
    const int quad = lane >> 4;
    const int c16  = lane & 15;
    const int bm = blockIdx.x * BM;
    const int bn = blockIdx.y * BN;
    const int wm = (wave >> 1) * 64;
    const int wn = (wave & 1) * 64;

    const int srow = lane >> 3;        // 0..7 within an 8-row chunk
    const int scol = (lane & 7) * 8;   // 0..56

    f32x4 acc[4][4] = {};

    for (int k0 = 0; k0 < DD; k0 += BKG) {
        __syncthreads();
        #pragma unroll
        for (int j = 0; j < 4; ++j) {
            int r0 = wave * 32 + j * 8;
            gld16(A + (size_t)(bm + r0 + srow) * DD + k0 + scol, &As[r0][0]);
            gld16(W + (size_t)(bn + r0 + srow) * DD + k0 + scol, &Bs[r0][0]);
        }
        __syncthreads();   // drains vmcnt -> async LDS writes complete

        #pragma unroll
        for (int ks = 0; ks < 2; ++ks) {
            bf16x8 af[4], bfr[4];
            #pragma unroll
            for (int tm = 0; tm < 4; ++tm)
                af[tm] = *(const bf16x8*)(&As[wm + tm * 16 + c16][ks * 32 + quad * 8]);
            #pragma unroll
            for (int tn = 0; tn < 4; ++tn)
                bfr[tn] = *(const bf16x8*)(&Bs[wn + tn * 16 + c16][ks * 32 + quad * 8]);
            #pragma unroll
            for (int tm = 0; tm < 4; ++tm)
                #pragma unroll
                for (int tn = 0; tn < 4; ++tn)
                    acc[tm][tn] = __builtin_amdgcn_mfma_f32_16x16x32_bf16(
                        af[tm], bfr[tn], acc[tm][tn], 0, 0, 0);
        }
    }

    float bia[4];
    #pragma unroll
    for (int tn = 0; tn < 4; ++tn)
        bia[tn] = bias[bn + wn + tn * 16 + c16];

    if (z < 2) {
        // Q carries 1/sqrt(DK) * log2(e) so attention can use exp2
        const float osc = (z == 0) ? 0.125f * 1.4426950408889634f : 1.0f;
        bf16_t* C = (z == 0) ? Qp : Kp;
        #pragma unroll
        for (int tm = 0; tm < 4; ++tm)
            #pragma unroll
            for (int r = 0; r < 4; ++r) {
                size_t base = (size_t)(bm + wm + tm * 16 + quad * 4 + r) * DD;
                #pragma unroll
                for (int tn = 0; tn < 4; ++tn)
                    C[base + bn + wn + tn * 16 + c16] =
                        (bf16_t)((acc[tm][tn][r] + bia[tn]) * osc);
            }
    } else {
        __syncthreads();
        #pragma unroll
        for (int tm = 0; tm < 4; ++tm)
            #pragma unroll
            for (int tn = 0; tn < 4; ++tn) {
                bf16x4 pk;
                #pragma unroll
                for (int r = 0; r < 4; ++r)
                    pk[r] = (bf16_t)(acc[tm][tn][r] + bia[tn]);
                *(bf16x4*)(&Ct[wn + tn * 16 + c16][wm + tm * 16 + quad * 4]) = pk;
            }
        __syncthreads();
        const int b_    = bm >> 11;
        const int sbase = bm & (SS - 1);
        #pragma unroll
        for (int p = 0; p < 4; ++p) {
            int col = p * 32 + (tid >> 3);
            int si  = (tid & 7) * 8;
            size_t rowoff = (size_t)(b_ * 1024 + bn + col) * SS + sbase;
            #pragma unroll
            for (int half = 0; half < 2; ++half) {
                int s = si + half * 64;
                *(bf16x8*)(&Vt[rowoff + s]) = *(const bf16x8*)(&Ct[col][s]);
            }
        }
    }
}

// ---------------------------------------------------------------------------
// Output projection: BM=128, BN=64, BK=64 -> grid (32,16)=512 blocks.
// Wave tile 64x32 (4 tm x 2 tn).
// ---------------------------------------------------------------------------
__global__ __launch_bounds__(256) void gemm_out(
    const bf16_t* __restrict__ A,    // Xa [M,K]
    const bf16_t* __restrict__ W,    // Wob [N,K]
    const float* __restrict__ bias,
    float* __restrict__ C)
{
    __shared__ __align__(16) bf16_t As[128][BKG];
    __shared__ __align__(16) bf16_t Bs[64][BKG];

    const int tid  = threadIdx.x;
    const int wave = tid >> 6;
    const int lane = tid & 63;
    const int quad = lane >> 4;
    const int c16  = lane & 15;
    const int bm = blockIdx.x * 128;
    const int bn = blockIdx.y * 64;
    const int wm = (wave >> 1) * 64;
    const int wn = (wave & 1) * 32;

    const int srow = lane >> 3;
    const int scol = (lane & 7) * 8;

    f32x4 acc[4][2] = {};

    for (int k0 = 0; k0 < DD; k0 += BKG) {
        __syncthreads();
        #pragma unroll
        for (int j = 0; j < 4; ++j) {
            int r0 = wave * 32 + j * 8;
            gld16(A + (size_t)(bm + r0 + srow) * DD + k0 + scol, &As[r0][0]);
        }
        #pragma unroll
        for (int j = 0; j < 2; ++j) {
            int r0 = wave * 16 + j * 8;
            gld16(W + (size_t)(bn + r0 + srow) * DD + k0 + scol, &Bs[r0][0]);
        }
        __syncthreads();

        #pragma unroll
        for (int ks = 0; ks < 2; ++ks) {
            bf16x8 af[4], bfr[2];
            #pragma unroll
            for (int tm = 0; tm < 4; ++tm)
                af[tm] = *(const bf16x8*)(&As[wm + tm * 16 + c16][ks * 32 + quad * 8]);
            #pragma unroll
            for (int tn = 0; tn < 2; ++tn)
                bfr[tn] = *(const bf16x8*)(&Bs[wn + tn * 16 + c16][ks * 32 + quad * 8]);
            #pragma unroll
            for (int tm = 0; tm < 4; ++tm)
                #pragma unroll
                for (int tn = 0; tn < 2; ++tn)
                    acc[tm][tn] = __builtin_amdgcn_mfma_f32_16x16x32_bf16(
                        af[tm], bfr[tn], acc[tm][tn], 0, 0, 0);
        }
    }

    float bia[2];
    #pragma unroll
    for (int tn = 0; tn < 2; ++tn)
        bia[tn] = bias[bn + wn + tn * 16 + c16];

    #pragma unroll
    for (int tm = 0; tm < 4; ++tm)
        #pragma unroll
        for (int r = 0; r < 4; ++r) {
            size_t base = (size_t)(bm + wm + tm * 16 + quad * 4 + r) * DD;
            #pragma unroll
            for (int tn = 0; tn < 2; ++tn)
                C[base + bn + wn + tn * 16 + c16] = acc[tm][tn][r] + bia[tn];
        }
}

// ---------------------------------------------------------------------------
// Split-K flash attention, paired qtiles, software-pipelined step.
// Grid = dim3(1024): bh = (id%8)*4 + id/256 (XCD-resident), pair = (id>>3)&31.
// Single-buffered K/V register tiles; P LDS double-buffered.
// ---------------------------------------------------------------------------
#define LDPS 40   // P row stride (bf16): rows=q(32), cols=key(32)
#define LDCF 68   // combine row stride (fp32)
#define PSLOT (4 * 32 * LDPS)   // bf16 elements per P slot

#define LOADK(UU)                                                              \
do {                                                                           \
    const int kb_ = (UU) * 32;                                                 \
    const bf16_t* kp0 = Kb + (size_t)(kb_ + c16) * DD;                         \
    const bf16_t* kp1 = Kb + (size_t)(kb_ + 16 + c16) * DD;                    \
    kf[0][0] = *(const bf16x8*)(kp0 + quad * 8);                               \
    kf[0][1] = *(const bf16x8*)(kp0 + 32 + quad * 8);                          \
    kf[1][0] = *(const bf16x8*)(kp1 + quad * 8);                               \
    kf[1][1] = *(const bf16x8*)(kp1 + 32 + quad * 8);                          \
} while (0)

#define LOADV(UU)                                                              \
do {                                                                           \
    const int kb_ = (UU) * 32;                                                 \
    _Pragma("unroll")                                                          \
    for (int tn = 0; tn < 4; ++tn)                                             \
        vf[tn] = *(const bf16x8*)(Vb + (size_t)(tn * 16 + c16) * SS            \
                                  + kb_ + quad * 8);                           \
} while (0)

// step u: QK[u] | pa<-PR | issue K[u+4] | exp2+P-store->PW | PV[u-4] | issue V[u]
#define ATTN_STEP(UU, PW, PR, DOPV)                                            \
do {                                                                           \
    const int kb_ = (UU) * 32;                                                 \
    f32x4 sc_[2][2];                                                           \
    _Pragma("unroll")                                                          \
    for (int tm = 0; tm < 2; ++tm)                                             \
        _Pragma("unroll")                                                      \
        for (int ct = 0; ct < 2; ++ct) {                                       \
            f32x4 s_ = {};                                                     \
            s_ = __builtin_amdgcn_mfma_f32_16x16x32_bf16(                      \
                     kf[ct][0], qf[tm][0], s_, 0, 0, 0);                       \
            s_ = __builtin_amdgcn_mfma_f32_16x16x32_bf16(                      \
                     kf[ct][1], qf[tm][1], s_, 0, 0, 0);                       \
            sc_[tm][ct] = s_;                                                  \
        }                                                                      \
    bf16x8 pa0_, pa1_;                                                         \
    if (DOPV) {                                                                \
        pa0_ = *(const bf16x8*)(PR);                                           \
        pa1_ = *(const bf16x8*)((PR) + 16 * LDPS);                             \
    }                                                                          \
    if ((UU) + 4 < U) LOADK((UU) + 4);                                         \
    const bool needmask_ = (kb_ == qbase);                                     \
    _Pragma("unroll")                                                          \
    for (int tm = 0; tm < 2; ++tm) {                                           \
        const int qrow_ = qbase + tm * 16 + c16;                               \
        _Pragma("unroll")                                                      \
        for (int ct = 0; ct < 2; ++ct) {                                       \
            bf16x4 w_;                                                         \
            _Pragma("unroll")                                                  \
            for (int r = 0; r < 4; ++r) {                                      \
                float s_ = sc_[tm][ct][r];                                     \
                if (needmask_ && (kb_ + ct * 16 + quad * 4 + r > qrow_))       \
                    s_ = -1e9f;                                                \
                float p_ = __builtin_amdgcn_exp2f(s_);                         \
                lsum2[tm] += p_;                                               \
                w_[r] = (bf16_t)p_;                                            \
            }                                                                  \
            *(bf16x4*)((PW) + tm * 16 * LDPS + ct * 16) = w_;                  \
        }                                                                      \
    }                                                                          \
    if (DOPV) {                                                                \
        _Pragma("unroll")                                                      \
        for (int tn = 0; tn < 4; ++tn) {                                       \
            oacc[0][tn] = __builtin_amdgcn_mfma_f32_16x16x32_bf16(             \
                pa0_, vf[tn], oacc[0][tn], 0, 0, 0);                           \
            oacc[1][tn] = __builtin_amdgcn_mfma_f32_16x16x32_bf16(             \
                pa1_, vf[tn], oacc[1][tn], 0, 0, 0);                           \
        }                                                                      \
    }                                                                          \
    LOADV(UU);                                                                 \
} while (0)

#define PVFIN(PR)                                                              \
do {                                                                           \
    bf16x8 pa0_ = *(const bf16x8*)(PR);                                        \
    bf16x8 pa1_ = *(const bf16x8*)((PR) + 16 * LDPS);                          \
    _Pragma("unroll")                                                          \
    for (int tn = 0; tn < 4; ++tn) {                                           \
        oacc[0][tn] = __builtin_amdgcn_mfma_f32_16x16x32_bf16(                 \
            pa0_, vf[tn], oacc[0][tn], 0, 0, 0);                               \
        oacc[1][tn] = __builtin_amdgcn_mfma_f32_16x16x32_bf16(                 \
            pa1_, vf[tn], oacc[1][tn], 0, 0, 0);                               \
    }                                                                          \
} while (0)

__global__ __launch_bounds__(256) void attn_fwd10(
    const bf16_t* __restrict__ Q,   // [B,S,D] (pre-scaled by 0.125*log2e)
    const bf16_t* __restrict__ K,   // [B,S,D]
    const bf16_t* __restrict__ Vt,  // [(b*1024 + h*64 + dk)][s]
    bf16_t* __restrict__ O)         // [B,S,D]
{
    const int flat = blockIdx.x;
    const int bh   = (flat & 7) * 4 + (flat >> 8);   // XCD-resident heads
    const int pair = (flat >> 3) & 31;
    const int b = bh >> 4;
    const int h = bh & 15;

    const int wave = threadIdx.x >> 6;
    const int lane = threadIdx.x & 63;
    const int quad = lane >> 4;
    const int c16  = lane & 15;

    // union: Ps[2][4][32][LDPS] bf16 (20.5 KB) / Cf[4][16][LDCF] fp32 (17.4 KB)
    __shared__ __align__(16) unsigned char smraw[2 * PSLOT * 2];
    bf16_t (*Ps)[4][32][LDPS] = (bf16_t(*)[4][32][LDPS])smraw;
    float  (*Cf)[16][LDCF]    = (float(*)[16][LDCF])smraw;
    __shared__ float Ls[4][32];

    const bf16_t* Kb = K  + (size_t)b * SS * DD + h * DKK;
    const bf16_t* Vb = Vt + (size_t)(b * 1024 + h * DKK) * SS;

    // per-lane LDS addresses for the two P slots
    bf16_t*       pw0 = &Ps[0][wave][c16][quad * 4];   // + tm*16*LDPS + ct*16
    const bf16_t* pr0 = &Ps[0][wave][c16][quad * 8];   // + tm*16*LDPS
    bf16_t*       pw1 = pw0 + PSLOT;
    const bf16_t* pr1 = pr0 + PSLOT;

    for (int t = 0; t < 2; ++t) {
        const int qt    = (t == 0) ? (63 - pair) : pair;   // heavy tile first
        const int qbase = qt * 32;
        const int U     = qt + 1;          // 32-key units

        // Q fragments (B operand of swapped MFMA): rows qbase..qbase+31
        bf16x8 qf[2][2];
        #pragma unroll
        for (int tm = 0; tm < 2; ++tm) {
            const bf16_t* qp = Q + ((size_t)b * SS + qbase + tm * 16 + c16) * DD + h * DKK;
            qf[tm][0] = *(const bf16x8*)(qp + quad * 8);
            qf[tm][1] = *(const bf16x8*)(qp + 32 + quad * 8);
        }

        f32x4 oacc[2][4] = {};
        float lsum2[2] = {0.f, 0.f};

        bf16x8 kf[2][2];   // K fragments, single buffer [ct][kstep]
        bf16x8 vf[4];      // V fragments, single buffer [tn]

        {
            int u = wave;
            if (u < U) {
                LOADK(u);
                // peeled first step: write slot0, load vf, no PV
                ATTN_STEP(u, pw0, pr1, 0);
                u += 4;
                for (;;) {
                    if (u >= U) { PVFIN(pr0); break; }
                    ATTN_STEP(u, pw1, pr0, 1);   // read slot0, write slot1
                    u += 4;
                    if (u >= U) { PVFIN(pr1); break; }
                    ATTN_STEP(u, pw0, pr1, 1);   // read slot1, write slot0
                    u += 4;
                }
            }
        }

        // ---- per-wave row sums (reduce over quads) -> Ls ----
        #pragma unroll
        for (int tm = 0; tm < 2; ++tm) {
            float l = lsum2[tm];
            l += __shfl_xor(l, 16, 64);
            l += __shfl_xor(l, 32, 64);
            if (lane < 16) Ls[wave][tm * 16 + lane] = l;
        }

        // ---- combine partials: two tm-passes through Cf (aliases Ps) ----
        const int row = threadIdx.x >> 4;        // 0..15
        const int col = (threadIdx.x & 15) * 4;  // 0..60
        #pragma unroll
        for (int tm = 0; tm < 2; ++tm) {
            __syncthreads();   // tm=0: unit loops done (Ps free); tm=1: pass-0 reads done
            #pragma unroll
            for (int tn = 0; tn < 4; ++tn)
                #pragma unroll
                for (int r = 0; r < 4; ++r)
                    Cf[wave][quad * 4 + r][tn * 16 + c16] = oacc[tm][tn][r];
            __syncthreads();
            f32x4 ssum = {};
            #pragma unroll
            for (int p = 0; p < 4; ++p)
                ssum += *(const f32x4*)(&Cf[p][row][col]);
            float l = Ls[0][tm * 16 + row] + Ls[1][tm * 16 + row]
                    + Ls[2][tm * 16 + row] + Ls[3][tm * 16 + row];
            float inv = 1.0f / l;
            bf16x4 o;
            #pragma unroll
            for (int i = 0; i < 4; ++i) o[i] = (bf16_t)(ssum[i] * inv);
            *(bf16x4*)(&O[((size_t)b * SS + qbase + tm * 16 + row) * DD + h * DKK + col]) = o;
        }
        __syncthreads();   // tile end: Ps/Cf/Ls reusable by next tile
    }
}

// ---------------------------------------------------------------------------
extern "C" void kernel_launch(void* const* d_in, const int* in_sizes, int n_in,
                              void* d_out, int out_size, void* d_ws, size_t ws_size,
                              hipStream_t stream) {
    (void)in_sizes; (void)n_in; (void)out_size; (void)d_ws; (void)ws_size;
    const float* q  = (const float*)d_in[0];
    const float* k  = (const float*)d_in[1];
    const float* v  = (const float*)d_in[2];
    const float* Wq = (const float*)d_in[4];
    const float* bq = (const float*)d_in[5];
    const float* Wk = (const float*)d_in[6];
    const float* bk = (const float*)d_in[7];
    const float* Wv = (const float*)d_in[8];
    const float* bv = (const float*)d_in[9];
    const float* Wo = (const float*)d_in[10];
    const float* bo = (const float*)d_in[11];

    bf16_t* ws;
    hipGetSymbolAddress((void**)&ws, HIP_SYMBOL(g_ws));
    bf16_t* Qp  = ws;
    bf16_t* Kp  = Qp + NELT;
    bf16_t* Vt  = Kp + NELT;
    bf16_t* Xa  = Vt + NELT;
    bf16_t* qb  = Xa + NELT;
    bf16_t* kb  = qb + NELT;
    bf16_t* vb  = kb + NELT;
    bf16_t* Wqb = vb + NELT;
    bf16_t* Wkb = Wqb + WELT;
    bf16_t* Wvb = Wkb + WELT;
    bf16_t* Wob = Wvb + WELT;

    cvt7<<<dim3(2048, 7), 256, 0, stream>>>(q, k, v, Wq, Wk, Wv, Wo,
                                            qb, kb, vb, Wqb, Wkb, Wvb, Wob);

    gemm_qkv3<<<dim3(MM / BM, DD / BN, 3), 256, 0, stream>>>(
        qb, kb, vb, Wqb, Wkb, Wvb, bq, bk, bv, Qp, Kp, Vt);

    attn_fwd10<<<dim3(1024), 256, 0, stream>>>(Qp, Kp, Vt, Xa);

    gemm_out<<<dim3(MM / 128, DD / 64), 256, 0, stream>>>(Xa, Wob, bo, (float*)d_out);
}

// Round 8
// 275.405 us; speedup vs baseline: 1.0371x; 1.0359x over previous
//
#include <hip/hip_runtime.h>
#include <hip/hip_bf16.h>

// MHA block: B=2, S=2048, D=1024, H=16, DK=64, causal. fp32 in/out.
// ROUND 17: consolidation. r13-r16 evidence: software-pipelining the attn
// step costs ~40 VGPR (regalloc shadows the early loads even when source
// single-buffers) -> 160 VGPR -> 3 blocks/CU on an exactly-4/CU grid ->
// net loss. Revert attn to the r12 structure (best measured: 76.9 us,
// VGPR 120, 4 blocks/CU) + two cheap orthogonal wins:
//   - exp2 softmax (log2e folded into Q pre-scale) removes 16 v_mul/step
//   - s_setprio(1) around MFMA clusters (attn waves independent -> m191 regime)
// GEMMs/cvt unchanged.

typedef __bf16 bf16_t;
typedef __bf16 bf16x4 __attribute__((ext_vector_type(4)));
typedef __bf16 bf16x8 __attribute__((ext_vector_type(8)));
typedef float f32x4 __attribute__((ext_vector_type(4)));

#define BB 2
#define SS 2048
#define DD 1024
#define HH 16
#define DKK 64
#define MM 4096            // tokens = B*S

#define NELT ((size_t)BB * SS * DD)     // 4,194,304
#define WELT ((size_t)DD * DD)          // 1,048,576

// layout: Qp | Kp | Vt | Xa | qb | kb | vb | Wqb | Wkb | Wvb | Wob
__device__ __align__(16) bf16_t g_ws[7 * NELT + 4 * WELT];

// async global->LDS, 16 B/lane; LDS dest = wave-uniform base + lane*16
__device__ __forceinline__ void gld16(const bf16_t* g, bf16_t* l) {
    __builtin_amdgcn_global_load_lds(
        (const __attribute__((address_space(1))) void*)g,
        (__attribute__((address_space(3))) void*)l, 16, 0, 0);
}

// ---------------------------------------------------------------------------
// fp32 -> bf16 pre-convert
// ---------------------------------------------------------------------------
__global__ __launch_bounds__(256) void cvt7(
    const float* __restrict__ q,  const float* __restrict__ k,  const float* __restrict__ v,
    const float* __restrict__ Wq, const float* __restrict__ Wk, const float* __restrict__ Wv,
    const float* __restrict__ Wo,
    bf16_t* __restrict__ qb, bf16_t* __restrict__ kb, bf16_t* __restrict__ vb,
    bf16_t* __restrict__ Wqb, bf16_t* __restrict__ Wkb, bf16_t* __restrict__ Wvb,
    bf16_t* __restrict__ Wob)
{
    const float* s; bf16_t* d; size_t n;
    switch (blockIdx.y) {
        case 0: s = q;  d = qb;  n = NELT; break;
        case 1: s = k;  d = kb;  n = NELT; break;
        case 2: s = v;  d = vb;  n = NELT; break;
        case 3: s = Wq; d = Wqb; n = WELT; break;
        case 4: s = Wk; d = Wkb; n = WELT; break;
        case 5: s = Wv; d = Wvb; n = WELT; break;
        default: s = Wo; d = Wob; n = WELT; break;
    }
    size_t e = ((size_t)blockIdx.x * 256 + threadIdx.x) * 8;
    if (e >= n) return;
    f32x4 a = *(const f32x4*)(s + e);
    f32x4 b = *(const f32x4*)(s + e + 4);
    bf16x8 o;
    #pragma unroll
    for (int i = 0; i < 4; ++i) { o[i] = (bf16_t)a[i]; o[4 + i] = (bf16_t)b[i]; }
    *(bf16x8*)(d + e) = o;
}

// ---------------------------------------------------------------------------
// Fused QKV projection: BM=BN=128, BK=64, 4 waves x (4x4 MFMA x 2 k-steps).
// z=0: Qp=(q@Wq^T+bq)*(0.125*log2e) ; z=1: Kp ; z=2: Vt (transposed store)
// ---------------------------------------------------------------------------
#define BM 128
#define BN 128
#define BKG 64
#define LDC 136

__global__ __launch_bounds__(256) void gemm_qkv3(
    const bf16_t* __restrict__ qb, const bf16_t* __restrict__ kb, const bf16_t* __restrict__ vb,
    const bf16_t* __restrict__ Wqb, const bf16_t* __restrict__ Wkb, const bf16_t* __restrict__ Wvb,
    const float* __restrict__ bq, const float* __restrict__ bk, const float* __restrict__ bv,
    bf16_t* __restrict__ Qp, bf16_t* __restrict__ Kp, bf16_t* __restrict__ Vt)
{
    const int z = blockIdx.z;
    const bf16_t* A    = (z == 0) ? qb  : (z == 1) ? kb  : vb;
    const bf16_t* W    = (z == 0) ? Wqb : (z == 1) ? Wkb : Wvb;
    const float*  bias = (z == 0) ? bq  : (z == 1) ? bk  : bv;

    // union: As[128][64] + Bs[128][64] (32 KB) vs Ct[128][LDC] (34.8 KB)
    __shared__ __align__(16) bf16_t smem[128 * LDC];
    bf16_t (*As)[BKG] = (bf16_t(*)[BKG])smem;
    bf16_t (*Bs)[BKG] = (bf16_t(*)[BKG])(smem + 128 * BKG);
    bf16_t (*Ct)[LDC] = (bf16_t(*)[LDC])smem;

    const int tid  = threadIdx.x;
    const int wave = tid >> 6;
    const int lane = tid & 63;
    const int quad = lane >> 4;
    const int c16  = lane & 15;
    const int bm = blockIdx.x * BM;
    const int bn = blockIdx.y * BN;
    const int wm = (wave >> 1) * 64;
    const int wn = (wave & 1) * 64;

    const int srow = lane >> 3;        // 0..7 within an 8-row chunk
    const int scol = (lane & 7) * 8;   // 0..56

    f32x4 acc[4][4] = {};

    for (int k0 = 0; k0 < DD; k0 += BKG) {
        __syncthreads();
        #pragma unroll
        for (int j = 0; j < 4; ++j) {
            int r0 = wave * 32 + j * 8;
            gld16(A + (size_t)(bm + r0 + srow) * DD + k0 + scol, &As[r0][0]);
            gld16(W + (size_t)(bn + r0 + srow) * DD + k0 + scol, &Bs[r0][0]);
        }
        __syncthreads();   // drains vmcnt -> async LDS writes complete

        #pragma unroll
        for (int ks = 0; ks < 2; ++ks) {
            bf16x8 af[4], bfr[4];
            #pragma unroll
            for (int tm = 0; tm < 4; ++tm)
                af[tm] = *(const bf16x8*)(&As[wm + tm * 16 + c16][ks * 32 + quad * 8]);
            #pragma unroll
            for (int tn = 0; tn < 4; ++tn)
                bfr[tn] = *(const bf16x8*)(&Bs[wn + tn * 16 + c16][ks * 32 + quad * 8]);
            #pragma unroll
            for (int tm = 0; tm < 4; ++tm)
                #pragma unroll
                for (int tn = 0; tn < 4; ++tn)
                    acc[tm][tn] = __builtin_amdgcn_mfma_f32_16x16x32_bf16(
                        af[tm], bfr[tn], acc[tm][tn], 0, 0, 0);
        }
    }

    float bia[4];
    #pragma unroll
    for (int tn = 0; tn < 4; ++tn)
        bia[tn] = bias[bn + wn + tn * 16 + c16];

    if (z < 2) {
        // Q carries 1/sqrt(DK) * log2(e) so attention can use exp2
        const float osc = (z == 0) ? 0.125f * 1.4426950408889634f : 1.0f;
        bf16_t* C = (z == 0) ? Qp : Kp;
        #pragma unroll
        for (int tm = 0; tm < 4; ++tm)
            #pragma unroll
            for (int r = 0; r < 4; ++r) {
                size_t base = (size_t)(bm + wm + tm * 16 + quad * 4 + r) * DD;
                #pragma unroll
                for (int tn = 0; tn < 4; ++tn)
                    C[base + bn + wn + tn * 16 + c16] =
                        (bf16_t)((acc[tm][tn][r] + bia[tn]) * osc);
            }
    } else {
        __syncthreads();
        #pragma unroll
        for (int tm = 0; tm < 4; ++tm)
            #pragma unroll
            for (int tn = 0; tn < 4; ++tn) {
                bf16x4 pk;
                #pragma unroll
                for (int r = 0; r < 4; ++r)
                    pk[r] = (bf16_t)(acc[tm][tn][r] + bia[tn]);
                *(bf16x4*)(&Ct[wn + tn * 16 + c16][wm + tm * 16 + quad * 4]) = pk;
            }
        __syncthreads();
        const int b_    = bm >> 11;
        const int sbase = bm & (SS - 1);
        #pragma unroll
        for (int p = 0; p < 4; ++p) {
            int col = p * 32 + (tid >> 3);
            int si  = (tid & 7) * 8;
            size_t rowoff = (size_t)(b_ * 1024 + bn + col) * SS + sbase;
            #pragma unroll
            for (int half = 0; half < 2; ++half) {
                int s = si + half * 64;
                *(bf16x8*)(&Vt[rowoff + s]) = *(const bf16x8*)(&Ct[col][s]);
            }
        }
    }
}

// ---------------------------------------------------------------------------
// Output projection: BM=128, BN=64, BK=64 -> grid (32,16)=512 blocks.
// Wave tile 64x32 (4 tm x 2 tn).
// ---------------------------------------------------------------------------
__global__ __launch_bounds__(256) void gemm_out(
    const bf16_t* __restrict__ A,    // Xa [M,K]
    const bf16_t* __restrict__ W,    // Wob [N,K]
    const float* __restrict__ bias,
    float* __restrict__ C)
{
    __shared__ __align__(16) bf16_t As[128][BKG];
    __shared__ __align__(16) bf16_t Bs[64][BKG];

    const int tid  = threadIdx.x;
    const int wave = tid >> 6;
    const int lane = tid & 63;
    const int quad = lane >> 4;
    const int c16  = lane & 15;
    const int bm = blockIdx.x * 128;
    const int bn = blockIdx.y * 64;
    const int wm = (wave >> 1) * 64;
    const int wn = (wave & 1) * 32;

    const int srow = lane >> 3;
    const int scol = (lane & 7) * 8;

    f32x4 acc[4][2] = {};

    for (int k0 = 0; k0 < DD; k0 += BKG) {
        __syncthreads();
        #pragma unroll
        for (int j = 0; j < 4; ++j) {
            int r0 = wave * 32 + j * 8;
            gld16(A + (size_t)(bm + r0 + srow) * DD + k0 + scol, &As[r0][0]);
        }
        #pragma unroll
        for (int j = 0; j < 2; ++j) {
            int r0 = wave * 16 + j * 8;
            gld16(W + (size_t)(bn + r0 + srow) * DD + k0 + scol, &Bs[r0][0]);
        }
        __syncthreads();

        #pragma unroll
        for (int ks = 0; ks < 2; ++ks) {
            bf16x8 af[4], bfr[2];
            #pragma unroll
            for (int tm = 0; tm < 4; ++tm)
                af[tm] = *(const bf16x8*)(&As[wm + tm * 16 + c16][ks * 32 + quad * 8]);
            #pragma unroll
            for (int tn = 0; tn < 2; ++tn)
                bfr[tn] = *(const bf16x8*)(&Bs[wn + tn * 16 + c16][ks * 32 + quad * 8]);
            #pragma unroll
            for (int tm = 0; tm < 4; ++tm)
                #pragma unroll
                for (int tn = 0; tn < 2; ++tn)
                    acc[tm][tn] = __builtin_amdgcn_mfma_f32_16x16x32_bf16(
                        af[tm], bfr[tn], acc[tm][tn], 0, 0, 0);
        }
    }

    float bia[2];
    #pragma unroll
    for (int tn = 0; tn < 2; ++tn)
        bia[tn] = bias[bn + wn + tn * 16 + c16];

    #pragma unroll
    for (int tm = 0; tm < 4; ++tm)
        #pragma unroll
        for (int r = 0; r < 4; ++r) {
            size_t base = (size_t)(bm + wm + tm * 16 + quad * 4 + r) * DD;
            #pragma unroll
            for (int tn = 0; tn < 2; ++tn)
                C[base + bn + wn + tn * 16 + c16] = acc[tm][tn][r] + bia[tn];
        }
}

// ---------------------------------------------------------------------------
// Split-K flash attention (r12 structure), paired qtiles.
// Grid = dim3(1024): bh = (id%8)*4 + id/256 (XCD-resident), pair = (id>>3)&31.
// Per tile: 4 waves take strided 32-key units. Swapped QK^T (mfma(K,Q)):
// packed bf16x4 P stores; same-step PV after lgkmcnt(0). Double-buffered K
// register fragments (prefetch next unit during current step). Shift-free
// softmax via exp2 (log2e pre-folded into Q): partials combine by ADDITION,
// 2-pass fp32 combine through 17 KB LDS (unioned with single P buffer).
// setprio(1) around MFMA clusters (independent waves -> m191 regime).
// ---------------------------------------------------------------------------
#define LDPS 40   // P row stride (bf16): rows=q(32), cols=key(32)
#define LDCF 68   // combine row stride (fp32)

#define LOADK(KF, UU)                                                          \
do {                                                                           \
    const int kb_ = (UU) * 32;                                                 \
    const bf16_t* kp0 = Kb + (size_t)(kb_ + c16) * DD;                         \
    const bf16_t* kp1 = Kb + (size_t)(kb_ + 16 + c16) * DD;                    \
    KF[0][0] = *(const bf16x8*)(kp0 + quad * 8);                               \
    KF[0][1] = *(const bf16x8*)(kp0 + 32 + quad * 8);                          \
    KF[1][0] = *(const bf16x8*)(kp1 + quad * 8);                               \
    KF[1][1] = *(const bf16x8*)(kp1 + 32 + quad * 8);                          \
} while (0)

// r12-style step: QK[u] on KFC | prefetch K[u+4]->KFN | load V[u] | exp2 +
// packed P store | lgkmcnt(0) | PV[u] same step.
#define ATTN_STEP(UU, KFC, KFN)                                                \
do {                                                                           \
    const int kb_ = (UU) * 32;                                                 \
    f32x4 sc_[2][2];                                                           \
    __builtin_amdgcn_s_setprio(1);                                             \
    _Pragma("unroll")                                                          \
    for (int tm = 0; tm < 2; ++tm)                                             \
        _Pragma("unroll")                                                      \
        for (int ct = 0; ct < 2; ++ct) {                                       \
            f32x4 s_ = {};                                                     \
            s_ = __builtin_amdgcn_mfma_f32_16x16x32_bf16(                      \
                     KFC[ct][0], qf[tm][0], s_, 0, 0, 0);                      \
            s_ = __builtin_amdgcn_mfma_f32_16x16x32_bf16(                      \
                     KFC[ct][1], qf[tm][1], s_, 0, 0, 0);                      \
            sc_[tm][ct] = s_;                                                  \
        }                                                                      \
    __builtin_amdgcn_s_setprio(0);                                             \
    if ((UU) + 4 < U) LOADK(KFN, (UU) + 4);                                    \
    bf16x8 vf_[4];                                                             \
    _Pragma("unroll")                                                          \
    for (int tn = 0; tn < 4; ++tn)                                             \
        vf_[tn] = *(const bf16x8*)(Vb + (size_t)(tn * 16 + c16) * SS           \
                                   + kb_ + quad * 8);                          \
    const bool needmask_ = (kb_ == qbase);                                     \
    _Pragma("unroll")                                                          \
    for (int tm = 0; tm < 2; ++tm) {                                           \
        const int qrow_ = qbase + tm * 16 + c16;                               \
        _Pragma("unroll")                                                      \
        for (int ct = 0; ct < 2; ++ct) {                                       \
            bf16x4 w_;                                                         \
            _Pragma("unroll")                                                  \
            for (int r = 0; r < 4; ++r) {                                      \
                float s_ = sc_[tm][ct][r];                                     \
                if (needmask_ && (kb_ + ct * 16 + quad * 4 + r > qrow_))       \
                    s_ = -1e9f;                                                \
                float p_ = __builtin_amdgcn_exp2f(s_);                         \
                lsum2[tm] += p_;                                               \
                w_[r] = (bf16_t)p_;                                            \
            }                                                                  \
            *(bf16x4*)(pw + tm * 16 * LDPS + ct * 16) = w_;                    \
        }                                                                      \
    }                                                                          \
    asm volatile("s_waitcnt lgkmcnt(0)" ::: "memory");                         \
    __builtin_amdgcn_s_setprio(1);                                             \
    _Pragma("unroll")                                                          \
    for (int tm = 0; tm < 2; ++tm) {                                           \
        bf16x8 pa_ = *(const bf16x8*)(pr + tm * 16 * LDPS);                    \
        _Pragma("unroll")                                                      \
        for (int tn = 0; tn < 4; ++tn)                                         \
            oacc[tm][tn] = __builtin_amdgcn_mfma_f32_16x16x32_bf16(            \
                pa_, vf_[tn], oacc[tm][tn], 0, 0, 0);                          \
    }                                                                          \
    __builtin_amdgcn_s_setprio(0);                                             \
} while (0)

__global__ __launch_bounds__(256) void attn_fwd11(
    const bf16_t* __restrict__ Q,   // [B,S,D] (pre-scaled by 0.125*log2e)
    const bf16_t* __restrict__ K,   // [B,S,D]
    const bf16_t* __restrict__ Vt,  // [(b*1024 + h*64 + dk)][s]
    bf16_t* __restrict__ O)         // [B,S,D]
{
    const int flat = blockIdx.x;
    const int bh   = (flat & 7) * 4 + (flat >> 8);   // XCD-resident heads
    const int pair = (flat >> 3) & 31;
    const int b = bh >> 4;
    const int h = bh & 15;

    const int wave = threadIdx.x >> 6;
    const int lane = threadIdx.x & 63;
    const int quad = lane >> 4;
    const int c16  = lane & 15;

    // union: Ps[4][32][LDPS] bf16 (10.2 KB) / Cf[4][16][LDCF] fp32 (17.4 KB)
    __shared__ __align__(16) unsigned char smraw[4 * 16 * LDCF * 4];
    bf16_t (*Ps)[32][LDPS] = (bf16_t(*)[32][LDPS])smraw;
    float  (*Cf)[16][LDCF] = (float(*)[16][LDCF])smraw;
    __shared__ float Ls[4][32];

    const bf16_t* Kb = K  + (size_t)b * SS * DD + h * DKK;
    const bf16_t* Vb = Vt + (size_t)(b * 1024 + h * DKK) * SS;

    // fixed per-lane LDS addresses (immediate offsets inside the loop)
    bf16_t*       pw = &Ps[wave][c16][quad * 4];   // + tm*16*LDPS + ct*16
    const bf16_t* pr = &Ps[wave][c16][quad * 8];   // + tm*16*LDPS

    for (int t = 0; t < 2; ++t) {
        const int qt    = (t == 0) ? (63 - pair) : pair;   // heavy tile first
        const int qbase = qt * 32;
        const int U     = qt + 1;          // 32-key units

        // Q fragments (B operand of swapped MFMA): rows qbase..qbase+31
        bf16x8 qf[2][2];
        #pragma unroll
        for (int tm = 0; tm < 2; ++tm) {
            const bf16_t* qp = Q + ((size_t)b * SS + qbase + tm * 16 + c16) * DD + h * DKK;
            qf[tm][0] = *(const bf16x8*)(qp + quad * 8);
            qf[tm][1] = *(const bf16x8*)(qp + 32 + quad * 8);
        }

        f32x4 oacc[2][4] = {};
        float lsum2[2] = {0.f, 0.f};

        bf16x8 kfA[2][2], kfB[2][2];   // K fragment double buffer [ct][kstep]

        {
            int u = wave;
            if (u < U) {
                LOADK(kfA, u);
                for (;;) {
                    ATTN_STEP(u, kfA, kfB); u += 4;
                    if (u >= U) break;
                    ATTN_STEP(u, kfB, kfA); u += 4;
                    if (u >= U) break;
                }
            }
        }

        // ---- per-wave row sums (reduce over quads) -> Ls ----
        #pragma unroll
        for (int tm = 0; tm < 2; ++tm) {
            float l = lsum2[tm];
            l += __shfl_xor(l, 16, 64);
            l += __shfl_xor(l, 32, 64);
            if (lane < 16) Ls[wave][tm * 16 + lane] = l;
        }

        // ---- combine partials: two tm-passes through Cf (aliases Ps) ----
        const int row = threadIdx.x >> 4;        // 0..15
        const int col = (threadIdx.x & 15) * 4;  // 0..60
        #pragma unroll
        for (int tm = 0; tm < 2; ++tm) {
            __syncthreads();   // tm=0: unit loops done (Ps free); tm=1: pass-0 reads done
            #pragma unroll
            for (int tn = 0; tn < 4; ++tn)
                #pragma unroll
                for (int r = 0; r < 4; ++r)
                    Cf[wave][quad * 4 + r][tn * 16 + c16] = oacc[tm][tn][r];
            __syncthreads();
            f32x4 ssum = {};
            #pragma unroll
            for (int p = 0; p < 4; ++p)
                ssum += *(const f32x4*)(&Cf[p][row][col]);
            float l = Ls[0][tm * 16 + row] + Ls[1][tm * 16 + row]
                    + Ls[2][tm * 16 + row] + Ls[3][tm * 16 + row];
            float inv = 1.0f / l;
            bf16x4 o;
            #pragma unroll
            for (int i = 0; i < 4; ++i) o[i] = (bf16_t)(ssum[i] * inv);
            *(bf16x4*)(&O[((size_t)b * SS + qbase + tm * 16 + row) * DD + h * DKK + col]) = o;
        }
        __syncthreads();   // tile end: Ps/Cf/Ls reusable by next tile
    }
}

// ---------------------------------------------------------------------------
extern "C" void kernel_launch(void* const* d_in, const int* in_sizes, int n_in,
                              void* d_out, int out_size, void* d_ws, size_t ws_size,
                              hipStream_t stream) {
    (void)in_sizes; (void)n_in; (void)out_size; (void)d_ws; (void)ws_size;
    const float* q  = (const float*)d_in[0];
    const float* k  = (const float*)d_in[1];
    const float* v  = (const float*)d_in[2];
    const float* Wq = (const float*)d_in[4];
    const float* bq = (const float*)d_in[5];
    const float* Wk = (const float*)d_in[6];
    const float* bk = (const float*)d_in[7];
    const float* Wv = (const float*)d_in[8];
    const float* bv = (const float*)d_in[9];
    const float* Wo = (const float*)d_in[10];
    const float* bo = (const float*)d_in[11];

    bf16_t* ws;
    hipGetSymbolAddress((void**)&ws, HIP_SYMBOL(g_ws));
    bf16_t* Qp  = ws;
    bf16_t* Kp  = Qp + NELT;
    bf16_t* Vt  = Kp + NELT;
    bf16_t* Xa  = Vt + NELT;
    bf16_t* qb  = Xa + NELT;
    bf16_t* kb  = qb + NELT;
    bf16_t* vb  = kb + NELT;
    bf16_t* Wqb = vb + NELT;
    bf16_t* Wkb = Wqb + WELT;
    bf16_t* Wvb = Wkb + WELT;
    bf16_t* Wob = Wvb + WELT;

    cvt7<<<dim3(2048, 7), 256, 0, stream>>>(q, k, v, Wq, Wk, Wv, Wo,
                                            qb, kb, vb, Wqb, Wkb, Wvb, Wob);

    gemm_qkv3<<<dim3(MM / BM, DD / BN, 3), 256, 0, stream>>>(
        qb, kb, vb, Wqb, Wkb, Wvb, bq, bk, bv, Qp, Kp, Vt);

    attn_fwd11<<<dim3(1024), 256, 0, stream>>>(Qp, Kp, Vt, Xa);

    gemm_out<<<dim3(MM / 128, DD / 64), 256, 0, stream>>>(Xa, Wob, bo, (float*)d_out);
}